// Round 1
// baseline (1613.897 us; speedup 1.0000x reference)
//
#include <hip/hip_runtime.h>
#include <math.h>

#define NN 100000
#define EE 1600000
#define DD 128

// ---------------- CSR build ----------------
__global__ __launch_bounds__(256) void hist_k(const int* __restrict__ dst, int* __restrict__ cnt) {
    int e = blockIdx.x * 256 + threadIdx.x;
    atomicAdd(&cnt[dst[e]], 1);
}

__global__ __launch_bounds__(1024) void scan_k(const int* __restrict__ cnt,
                                               int* __restrict__ offsets,
                                               int* __restrict__ cursor) {
    __shared__ int part[1024];
    int t = threadIdx.x;
    const int C = (NN + 1023) / 1024;  // 98
    int lo = t * C, hi = lo + C; if (hi > NN) hi = NN; if (lo > NN) lo = NN;
    int s = 0;
    for (int i = lo; i < hi; i++) s += cnt[i];
    part[t] = s;
    __syncthreads();
    // Hillis-Steele inclusive scan
    for (int off = 1; off < 1024; off <<= 1) {
        int v = (t >= off) ? part[t - off] : 0;
        __syncthreads();
        part[t] += v;
        __syncthreads();
    }
    int pre = (t == 0) ? 0 : part[t - 1];
    for (int i = lo; i < hi; i++) {
        offsets[i] = pre; cursor[i] = pre;
        pre += cnt[i];
    }
    if (t == 1023) offsets[NN] = pre;
}

__global__ __launch_bounds__(256) void scatter_k(const int* __restrict__ src,
                                                 const int* __restrict__ dst,
                                                 int* __restrict__ cursor,
                                                 int* __restrict__ ssrc) {
    int e = blockIdx.x * 256 + threadIdx.x;
    int d = dst[e];
    int p = atomicAdd(&cursor[d], 1);
    ssrc[p] = src[e];
}

// ---------------- GEMM: Y = X @ W (+bias+leaky | +alpha dots) ----------------
// block = 256 threads, tile = 32 rows x 128 cols, thread = 4 rows x 4 cols
// MODE 0: Y = leaky(X@W + bias, 0.01)
// MODE 1: Y = X@W ; alpha_src[r] = dot(Y[r], av_src); alpha_dst[r] = dot(Y[r], av_dst)
template <int MODE>
__global__ __launch_bounds__(256) void gemm_k(const float* __restrict__ X,
                                              const float* __restrict__ W,
                                              const float* __restrict__ bias,
                                              const float* __restrict__ av_src,
                                              const float* __restrict__ av_dst,
                                              float* __restrict__ Y,
                                              float* __restrict__ alpha_src,
                                              float* __restrict__ alpha_dst) {
    __shared__ float sW[DD * DD];   // 64 KB
    __shared__ float sX[32 * DD];   // 16 KB
    int t = threadIdx.x;
    int row0 = blockIdx.x * 32;

    const float4* W4 = (const float4*)W;
    float4* sW4 = (float4*)sW;
    for (int i = t; i < DD * DD / 4; i += 256) sW4[i] = W4[i];
    const float4* X4 = (const float4*)(X + (size_t)row0 * DD);
    float4* sX4 = (float4*)sX;
    for (int i = t; i < 32 * DD / 4; i += 256) sX4[i] = X4[i];
    __syncthreads();

    int wave = t >> 6, lane = t & 63;
    int half = lane >> 5;
    int cg = lane & 31;
    int c0 = cg * 4;
    int r0 = wave * 8 + half * 4;  // local rows r0..r0+3

    float acc[4][4] = {};
#pragma unroll 8
    for (int k = 0; k < DD; k += 4) {
        float4 w0 = *(const float4*)&sW[(k + 0) * DD + c0];
        float4 w1 = *(const float4*)&sW[(k + 1) * DD + c0];
        float4 w2 = *(const float4*)&sW[(k + 2) * DD + c0];
        float4 w3 = *(const float4*)&sW[(k + 3) * DD + c0];
#pragma unroll
        for (int r = 0; r < 4; r++) {
            float4 xv = *(const float4*)&sX[(r0 + r) * DD + k];
            acc[r][0] += xv.x * w0.x; acc[r][1] += xv.x * w0.y; acc[r][2] += xv.x * w0.z; acc[r][3] += xv.x * w0.w;
            acc[r][0] += xv.y * w1.x; acc[r][1] += xv.y * w1.y; acc[r][2] += xv.y * w1.z; acc[r][3] += xv.y * w1.w;
            acc[r][0] += xv.z * w2.x; acc[r][1] += xv.z * w2.y; acc[r][2] += xv.z * w2.z; acc[r][3] += xv.z * w2.w;
            acc[r][0] += xv.w * w3.x; acc[r][1] += xv.w * w3.y; acc[r][2] += xv.w * w3.z; acc[r][3] += xv.w * w3.w;
        }
    }

    if (MODE == 0) {
        float4 b4 = *(const float4*)(bias + c0);
#pragma unroll
        for (int r = 0; r < 4; r++) {
            float4 o;
            o.x = acc[r][0] + b4.x; o.y = acc[r][1] + b4.y;
            o.z = acc[r][2] + b4.z; o.w = acc[r][3] + b4.w;
            o.x = o.x > 0.f ? o.x : 0.01f * o.x;
            o.y = o.y > 0.f ? o.y : 0.01f * o.y;
            o.z = o.z > 0.f ? o.z : 0.01f * o.z;
            o.w = o.w > 0.f ? o.w : 0.01f * o.w;
            *(float4*)&Y[(size_t)(row0 + r0 + r) * DD + c0] = o;
        }
    } else {
        float4 as4 = *(const float4*)(av_src + c0);
        float4 ad4 = *(const float4*)(av_dst + c0);
        float pa[4], pb[4];
#pragma unroll
        for (int r = 0; r < 4; r++) {
            float4 o;
            o.x = acc[r][0]; o.y = acc[r][1]; o.z = acc[r][2]; o.w = acc[r][3];
            *(float4*)&Y[(size_t)(row0 + r0 + r) * DD + c0] = o;
            pa[r] = o.x * as4.x + o.y * as4.y + o.z * as4.z + o.w * as4.w;
            pb[r] = o.x * ad4.x + o.y * ad4.y + o.z * ad4.z + o.w * ad4.w;
        }
#pragma unroll
        for (int off = 16; off >= 1; off >>= 1) {
#pragma unroll
            for (int r = 0; r < 4; r++) {
                pa[r] += __shfl_xor(pa[r], off);
                pb[r] += __shfl_xor(pb[r], off);
            }
        }
        if (cg == 0) {
#pragma unroll
            for (int r = 0; r < 4; r++) {
                alpha_src[row0 + r0 + r] = pa[r];
                alpha_dst[row0 + r0 + r] = pb[r];
            }
        }
    }
}

// ---------------- Per-dst aggregation + softmax + bias + LN + leaky ----------------
// one wave (64 lanes) per dst node; lane c owns channels 2c, 2c+1
__global__ __launch_bounds__(256) void agg_k(const float* __restrict__ tmp,
                                             const int* __restrict__ ssrc,
                                             const int* __restrict__ offsets,
                                             const float* __restrict__ alpha_src,
                                             const float* __restrict__ alpha_dst,
                                             const float* __restrict__ bias,
                                             const float* __restrict__ gamma,
                                             const float* __restrict__ beta,
                                             float* __restrict__ out) {
    int wid = (blockIdx.x * 256 + threadIdx.x) >> 6;
    int lane = threadIdx.x & 63;
    int beg = offsets[wid], end = offsets[wid + 1];
    float adst = alpha_dst[wid];

    // pass 1: segment max
    float m = -INFINITY;
    for (int j = beg + lane; j < end; j += 64) {
        int s = ssrc[j];
        float e = alpha_src[s] + adst;
        e = e > 0.f ? e : 0.2f * e;
        m = fmaxf(m, e);
    }
#pragma unroll
    for (int off = 32; off >= 1; off >>= 1) m = fmaxf(m, __shfl_xor(m, off));

    // pass 2: exp weights + accumulate (unnormalized), track denom
    float2 acc = make_float2(0.f, 0.f);
    float dsum = 0.f;
    const float2* tmp2 = (const float2*)tmp;
    for (int base = beg; base < end; base += 64) {
        int j = base + lane;
        float ex = 0.f; int s = 0;
        if (j < end) {
            s = ssrc[j];
            float e = alpha_src[s] + adst;
            e = e > 0.f ? e : 0.2f * e;
            ex = __expf(e - m);
        }
        dsum += ex;
        int cntr = end - base; if (cntr > 64) cntr = 64;
        for (int jj = 0; jj < cntr; jj++) {
            float w = __shfl(ex, jj);
            int ss = __shfl(s, jj);
            float2 hv = tmp2[(size_t)ss * 64 + lane];
            acc.x += w * hv.x;
            acc.y += w * hv.y;
        }
    }
#pragma unroll
    for (int off = 32; off >= 1; off >>= 1) dsum += __shfl_xor(dsum, off);
    float inv = 1.0f / (dsum + 1e-16f);

    acc.x = acc.x * inv + bias[2 * lane];
    acc.y = acc.y * inv + bias[2 * lane + 1];

    // layernorm over 128 channels (2 per lane)
    float s1 = acc.x + acc.y;
#pragma unroll
    for (int off = 32; off >= 1; off >>= 1) s1 += __shfl_xor(s1, off);
    float mu = s1 * (1.0f / 128.0f);
    float dx = acc.x - mu, dy = acc.y - mu;
    float s2 = dx * dx + dy * dy;
#pragma unroll
    for (int off = 32; off >= 1; off >>= 1) s2 += __shfl_xor(s2, off);
    float rstd = rsqrtf(s2 * (1.0f / 128.0f) + 1e-5f);

    float yx = dx * rstd * gamma[2 * lane] + beta[2 * lane];
    float yy = dy * rstd * gamma[2 * lane + 1] + beta[2 * lane + 1];
    yx = yx > 0.f ? yx : 0.01f * yx;
    yy = yy > 0.f ? yy : 0.01f * yy;
    ((float2*)out)[(size_t)wid * 64 + lane] = make_float2(yx, yy);
}

extern "C" void kernel_launch(void* const* d_in, const int* in_sizes, int n_in,
                              void* d_out, int out_size, void* d_ws, size_t ws_size,
                              hipStream_t stream) {
    const float* x       = (const float*)d_in[0];
    const int*   ei      = (const int*)d_in[1];
    const float* W_in    = (const float*)d_in[2];
    const float* b_in    = (const float*)d_in[3];
    const float* Wl      = (const float*)d_in[4];
    const float* att_src = (const float*)d_in[5];
    const float* att_dst = (const float*)d_in[6];
    const float* bias_l  = (const float*)d_in[7];
    const float* gamma   = (const float*)d_in[8];
    const float* beta    = (const float*)d_in[9];
    float* out = (float*)d_out;

    char* ws = (char*)d_ws;
    float* tmp       = (float*)ws; ws += (size_t)NN * DD * 4;   // 51.2 MB
    float* alpha_src = (float*)ws; ws += (size_t)NN * 4;
    float* alpha_dst = (float*)ws; ws += (size_t)NN * 4;
    int*   cnt       = (int*)ws;   ws += (size_t)NN * 4;
    int*   offsets   = (int*)ws;   ws += (size_t)(NN + 4) * 4;
    int*   cursor    = (int*)ws;   ws += (size_t)NN * 4;
    int*   ssrc      = (int*)ws;   ws += (size_t)EE * 4;

    const int* esrc = ei;
    const int* edst = ei + EE;

    // CSR by dst (edges constant within a launch)
    hipMemsetAsync(cnt, 0, (size_t)NN * 4, stream);
    hist_k<<<EE / 256, 256, 0, stream>>>(edst, cnt);
    scan_k<<<1, 1024, 0, stream>>>(cnt, offsets, cursor);
    scatter_k<<<EE / 256, 256, 0, stream>>>(esrc, edst, cursor, ssrc);

    // input projection: h0 = leaky(x @ W_in + b_in)
    gemm_k<0><<<NN / 32, 256, 0, stream>>>(x, W_in, b_in, nullptr, nullptr, out, nullptr, nullptr);

    for (int i = 0; i < 4; i++) {
        gemm_k<1><<<NN / 32, 256, 0, stream>>>(out, Wl + (size_t)i * DD * DD, nullptr,
                                               att_src + (size_t)i * DD, att_dst + (size_t)i * DD,
                                               tmp, alpha_src, alpha_dst);
        agg_k<<<NN / 4, 256, 0, stream>>>(tmp, ssrc, offsets, alpha_src, alpha_dst,
                                          bias_l + (size_t)i * DD, gamma + (size_t)i * DD,
                                          beta + (size_t)i * DD, out);
    }
}

// Round 2
// 1313.691 us; speedup vs baseline: 1.2285x; 1.2285x over previous
//
#include <hip/hip_runtime.h>
#include <math.h>

#define NN 100000
#define EE 1600000
#define DD 128
#define NB ((NN + 255) / 256)   // 391 scan blocks

// ---------------- CSR build ----------------
__global__ __launch_bounds__(256) void hist_k(const int* __restrict__ dst, int* __restrict__ cnt) {
    int e = blockIdx.x * 256 + threadIdx.x;
    atomicAdd(&cnt[dst[e]], 1);
}

// phase A: per-block partial sums of cnt
__global__ __launch_bounds__(256) void scanA_k(const int* __restrict__ cnt, int* __restrict__ bsum) {
    int i = blockIdx.x * 256 + threadIdx.x;
    int c = (i < NN) ? cnt[i] : 0;
#pragma unroll
    for (int off = 32; off >= 1; off >>= 1) c += __shfl_xor(c, off);
    __shared__ int ws[4];
    if ((threadIdx.x & 63) == 0) ws[threadIdx.x >> 6] = c;
    __syncthreads();
    if (threadIdx.x == 0) bsum[blockIdx.x] = ws[0] + ws[1] + ws[2] + ws[3];
}

// phase B: exclusive scan of NB block sums (single small block)
__global__ __launch_bounds__(512) void scanB_k(const int* __restrict__ bsum, int* __restrict__ bpre,
                                               int* __restrict__ offsets) {
    __shared__ int sh[512];
    int t = threadIdx.x;
    sh[t] = (t < NB) ? bsum[t] : 0;
    __syncthreads();
    for (int off = 1; off < 512; off <<= 1) {
        int v = (t >= off) ? sh[t - off] : 0;
        __syncthreads();
        sh[t] += v;
        __syncthreads();
    }
    if (t < NB) bpre[t] = (t == 0) ? 0 : sh[t - 1];
    if (t == 0) offsets[NN] = EE;
}

// phase C: in-block exclusive scan + add block prefix
__global__ __launch_bounds__(256) void scanC_k(const int* __restrict__ cnt, const int* __restrict__ bpre,
                                               int* __restrict__ offsets, int* __restrict__ cursor) {
    int t = threadIdx.x;
    int i = blockIdx.x * 256 + t;
    int lane = t & 63, wave = t >> 6;
    int c = (i < NN) ? cnt[i] : 0;
    int x = c;
    // wave-inclusive scan
#pragma unroll
    for (int off = 1; off < 64; off <<= 1) {
        int v = __shfl_up(x, off);
        if (lane >= off) x += v;
    }
    __shared__ int wsum[4];
    if (lane == 63) wsum[wave] = x;
    __syncthreads();
    __shared__ int wpre[4];
    if (t == 0) {
        wpre[0] = 0;
        wpre[1] = wsum[0];
        wpre[2] = wsum[0] + wsum[1];
        wpre[3] = wsum[0] + wsum[1] + wsum[2];
    }
    __syncthreads();
    if (i < NN) {
        int off = bpre[blockIdx.x] + wpre[wave] + (x - c);  // exclusive
        offsets[i] = off;
        cursor[i] = off;
    }
}

__global__ __launch_bounds__(256) void scatter_k(const int* __restrict__ src,
                                                 const int* __restrict__ dst,
                                                 int* __restrict__ cursor,
                                                 int* __restrict__ ssrc) {
    int e = blockIdx.x * 256 + threadIdx.x;
    int d = dst[e];
    int p = atomicAdd(&cursor[d], 1);
    ssrc[p] = src[e];
}

// ---------------- GEMM: Y = X @ W (+bias+leaky | +alpha dots) ----------------
// block = 256 threads, tile = 32 rows x 128 cols, thread = 4 rows x 4 cols
template <int MODE>
__global__ __launch_bounds__(256) void gemm_k(const float* __restrict__ X,
                                              const float* __restrict__ W,
                                              const float* __restrict__ bias,
                                              const float* __restrict__ av_src,
                                              const float* __restrict__ av_dst,
                                              float* __restrict__ Y,
                                              float* __restrict__ alpha_src,
                                              float* __restrict__ alpha_dst) {
    __shared__ float sW[DD * DD];   // 64 KB
    __shared__ float sX[32 * DD];   // 16 KB
    int t = threadIdx.x;
    int row0 = blockIdx.x * 32;

    const float4* W4 = (const float4*)W;
    float4* sW4 = (float4*)sW;
    for (int i = t; i < DD * DD / 4; i += 256) sW4[i] = W4[i];
    const float4* X4 = (const float4*)(X + (size_t)row0 * DD);
    float4* sX4 = (float4*)sX;
    for (int i = t; i < 32 * DD / 4; i += 256) sX4[i] = X4[i];
    __syncthreads();

    int wave = t >> 6, lane = t & 63;
    int half = lane >> 5;
    int cg = lane & 31;
    int c0 = cg * 4;
    int r0 = wave * 8 + half * 4;

    float acc[4][4] = {};
#pragma unroll 8
    for (int k = 0; k < DD; k += 4) {
        float4 w0 = *(const float4*)&sW[(k + 0) * DD + c0];
        float4 w1 = *(const float4*)&sW[(k + 1) * DD + c0];
        float4 w2 = *(const float4*)&sW[(k + 2) * DD + c0];
        float4 w3 = *(const float4*)&sW[(k + 3) * DD + c0];
#pragma unroll
        for (int r = 0; r < 4; r++) {
            float4 xv = *(const float4*)&sX[(r0 + r) * DD + k];
            acc[r][0] += xv.x * w0.x; acc[r][1] += xv.x * w0.y; acc[r][2] += xv.x * w0.z; acc[r][3] += xv.x * w0.w;
            acc[r][0] += xv.y * w1.x; acc[r][1] += xv.y * w1.y; acc[r][2] += xv.y * w1.z; acc[r][3] += xv.y * w1.w;
            acc[r][0] += xv.z * w2.x; acc[r][1] += xv.z * w2.y; acc[r][2] += xv.z * w2.z; acc[r][3] += xv.z * w2.w;
            acc[r][0] += xv.w * w3.x; acc[r][1] += xv.w * w3.y; acc[r][2] += xv.w * w3.z; acc[r][3] += xv.w * w3.w;
        }
    }

    if (MODE == 0) {
        float4 b4 = *(const float4*)(bias + c0);
#pragma unroll
        for (int r = 0; r < 4; r++) {
            float4 o;
            o.x = acc[r][0] + b4.x; o.y = acc[r][1] + b4.y;
            o.z = acc[r][2] + b4.z; o.w = acc[r][3] + b4.w;
            o.x = o.x > 0.f ? o.x : 0.01f * o.x;
            o.y = o.y > 0.f ? o.y : 0.01f * o.y;
            o.z = o.z > 0.f ? o.z : 0.01f * o.z;
            o.w = o.w > 0.f ? o.w : 0.01f * o.w;
            *(float4*)&Y[(size_t)(row0 + r0 + r) * DD + c0] = o;
        }
    } else {
        float4 as4 = *(const float4*)(av_src + c0);
        float4 ad4 = *(const float4*)(av_dst + c0);
        float pa[4], pb[4];
#pragma unroll
        for (int r = 0; r < 4; r++) {
            float4 o;
            o.x = acc[r][0]; o.y = acc[r][1]; o.z = acc[r][2]; o.w = acc[r][3];
            *(float4*)&Y[(size_t)(row0 + r0 + r) * DD + c0] = o;
            pa[r] = o.x * as4.x + o.y * as4.y + o.z * as4.z + o.w * as4.w;
            pb[r] = o.x * ad4.x + o.y * ad4.y + o.z * ad4.z + o.w * ad4.w;
        }
#pragma unroll
        for (int off = 16; off >= 1; off >>= 1) {
#pragma unroll
            for (int r = 0; r < 4; r++) {
                pa[r] += __shfl_xor(pa[r], off);
                pb[r] += __shfl_xor(pb[r], off);
            }
        }
        if (cg == 0) {
#pragma unroll
            for (int r = 0; r < 4; r++) {
                alpha_src[row0 + r0 + r] = pa[r];
                alpha_dst[row0 + r0 + r] = pb[r];
            }
        }
    }
}

// ---------------- Per-dst aggregation + softmax + bias + LN + leaky ----------------
// one wave per dst node; lane c owns channels 2c, 2c+1
__global__ __launch_bounds__(256) void agg_k(const float* __restrict__ tmp,
                                             const int* __restrict__ ssrc,
                                             const int* __restrict__ offsets,
                                             const float* __restrict__ alpha_src,
                                             const float* __restrict__ alpha_dst,
                                             const float* __restrict__ bias,
                                             const float* __restrict__ gamma,
                                             const float* __restrict__ beta,
                                             float* __restrict__ out) {
    int wid = (blockIdx.x * 256 + threadIdx.x) >> 6;
    int lane = threadIdx.x & 63;
    int beg = offsets[wid], end = offsets[wid + 1];
    float adst = alpha_dst[wid];

    // pass 1: segment max
    float m = -INFINITY;
    for (int j = beg + lane; j < end; j += 64) {
        int s = ssrc[j];
        float e = alpha_src[s] + adst;
        e = e > 0.f ? e : 0.2f * e;
        m = fmaxf(m, e);
    }
#pragma unroll
    for (int off = 32; off >= 1; off >>= 1) m = fmaxf(m, __shfl_xor(m, off));

    // pass 2: exp weights + accumulate (unnormalized), track denom
    float2 accA = make_float2(0.f, 0.f);
    float2 accB = make_float2(0.f, 0.f);
    float dsum = 0.f;
    const float2* tmp2 = (const float2*)tmp;
    for (int base = beg; base < end; base += 64) {
        int j = base + lane;
        float ex = 0.f; int s = 0;
        if (j < end) {
            s = ssrc[j];
            float e = alpha_src[s] + adst;
            e = e > 0.f ? e : 0.2f * e;
            ex = __expf(e - m);
        }
        dsum += ex;
        int cntr = end - base; if (cntr > 64) cntr = 64;
        int jj = 0;
        // 4-way unrolled broadcast: 4 independent gathers in flight
        for (; jj + 3 < cntr; jj += 4) {
            float w0 = __shfl(ex, jj),     w1 = __shfl(ex, jj + 1);
            float w2 = __shfl(ex, jj + 2), w3 = __shfl(ex, jj + 3);
            int   s0 = __shfl(s, jj),      s1 = __shfl(s, jj + 1);
            int   s2 = __shfl(s, jj + 2),  s3 = __shfl(s, jj + 3);
            float2 h0 = tmp2[(size_t)s0 * 64 + lane];
            float2 h1 = tmp2[(size_t)s1 * 64 + lane];
            float2 h2 = tmp2[(size_t)s2 * 64 + lane];
            float2 h3 = tmp2[(size_t)s3 * 64 + lane];
            accA.x += w0 * h0.x; accA.y += w0 * h0.y;
            accB.x += w1 * h1.x; accB.y += w1 * h1.y;
            accA.x += w2 * h2.x; accA.y += w2 * h2.y;
            accB.x += w3 * h3.x; accB.y += w3 * h3.y;
        }
        for (; jj < cntr; jj++) {
            float w = __shfl(ex, jj);
            int ss = __shfl(s, jj);
            float2 hv = tmp2[(size_t)ss * 64 + lane];
            accA.x += w * hv.x;
            accA.y += w * hv.y;
        }
    }
#pragma unroll
    for (int off = 32; off >= 1; off >>= 1) dsum += __shfl_xor(dsum, off);
    float inv = 1.0f / (dsum + 1e-16f);

    float ax = (accA.x + accB.x) * inv + bias[2 * lane];
    float ay = (accA.y + accB.y) * inv + bias[2 * lane + 1];

    // layernorm over 128 channels (2 per lane)
    float s1 = ax + ay;
#pragma unroll
    for (int off = 32; off >= 1; off >>= 1) s1 += __shfl_xor(s1, off);
    float mu = s1 * (1.0f / 128.0f);
    float dx = ax - mu, dy = ay - mu;
    float s2 = dx * dx + dy * dy;
#pragma unroll
    for (int off = 32; off >= 1; off >>= 1) s2 += __shfl_xor(s2, off);
    float rstd = rsqrtf(s2 * (1.0f / 128.0f) + 1e-5f);

    float yx = dx * rstd * gamma[2 * lane] + beta[2 * lane];
    float yy = dy * rstd * gamma[2 * lane + 1] + beta[2 * lane + 1];
    yx = yx > 0.f ? yx : 0.01f * yx;
    yy = yy > 0.f ? yy : 0.01f * yy;
    ((float2*)out)[(size_t)wid * 64 + lane] = make_float2(yx, yy);
}

extern "C" void kernel_launch(void* const* d_in, const int* in_sizes, int n_in,
                              void* d_out, int out_size, void* d_ws, size_t ws_size,
                              hipStream_t stream) {
    const float* x       = (const float*)d_in[0];
    const int*   ei      = (const int*)d_in[1];
    const float* W_in    = (const float*)d_in[2];
    const float* b_in    = (const float*)d_in[3];
    const float* Wl      = (const float*)d_in[4];
    const float* att_src = (const float*)d_in[5];
    const float* att_dst = (const float*)d_in[6];
    const float* bias_l  = (const float*)d_in[7];
    const float* gamma   = (const float*)d_in[8];
    const float* beta    = (const float*)d_in[9];
    float* out = (float*)d_out;

    char* ws = (char*)d_ws;
    float* tmp       = (float*)ws; ws += (size_t)NN * DD * 4;   // 51.2 MB
    float* alpha_src = (float*)ws; ws += (size_t)NN * 4;
    float* alpha_dst = (float*)ws; ws += (size_t)NN * 4;
    int*   cnt       = (int*)ws;   ws += (size_t)NN * 4;
    int*   offsets   = (int*)ws;   ws += (size_t)(NN + 4) * 4;
    int*   cursor    = (int*)ws;   ws += (size_t)NN * 4;
    int*   ssrc      = (int*)ws;   ws += (size_t)EE * 4;
    int*   bsum      = (int*)ws;   ws += (size_t)(NB + 8) * 4;
    int*   bpre      = (int*)ws;   ws += (size_t)(NB + 8) * 4;

    const int* esrc = ei;
    const int* edst = ei + EE;

    // CSR by dst (edges constant within a launch)
    hipMemsetAsync(cnt, 0, (size_t)NN * 4, stream);
    hist_k<<<EE / 256, 256, 0, stream>>>(edst, cnt);
    scanA_k<<<NB, 256, 0, stream>>>(cnt, bsum);
    scanB_k<<<1, 512, 0, stream>>>(bsum, bpre, offsets);
    scanC_k<<<NB, 256, 0, stream>>>(cnt, bpre, offsets, cursor);
    scatter_k<<<EE / 256, 256, 0, stream>>>(esrc, edst, cursor, ssrc);

    // input projection: h0 = leaky(x @ W_in + b_in)
    gemm_k<0><<<NN / 32, 256, 0, stream>>>(x, W_in, b_in, nullptr, nullptr, out, nullptr, nullptr);

    for (int i = 0; i < 4; i++) {
        gemm_k<1><<<NN / 32, 256, 0, stream>>>(out, Wl + (size_t)i * DD * DD, nullptr,
                                               att_src + (size_t)i * DD, att_dst + (size_t)i * DD,
                                               tmp, alpha_src, alpha_dst);
        agg_k<<<NN / 4, 256, 0, stream>>>(tmp, ssrc, offsets, alpha_src, alpha_dst,
                                          bias_l + (size_t)i * DD, gamma + (size_t)i * DD,
                                          beta + (size_t)i * DD, out);
    }
}

// Round 3
// 1036.566 us; speedup vs baseline: 1.5570x; 1.2673x over previous
//
#include <hip/hip_runtime.h>
#include <math.h>

#define NN 100000
#define EE 1600000
#define DD 128
#define NB ((NN + 255) / 256)   // 391 scan blocks

// ---------------- CSR build ----------------
__global__ __launch_bounds__(256) void hist_k(const int* __restrict__ dst, int* __restrict__ cnt) {
    int e = blockIdx.x * 256 + threadIdx.x;
    atomicAdd(&cnt[dst[e]], 1);
}

// phase A: per-block partial sums of cnt
__global__ __launch_bounds__(256) void scanA_k(const int* __restrict__ cnt, int* __restrict__ bsum) {
    int i = blockIdx.x * 256 + threadIdx.x;
    int c = (i < NN) ? cnt[i] : 0;
#pragma unroll
    for (int off = 32; off >= 1; off >>= 1) c += __shfl_xor(c, off);
    __shared__ int ws[4];
    if ((threadIdx.x & 63) == 0) ws[threadIdx.x >> 6] = c;
    __syncthreads();
    if (threadIdx.x == 0) bsum[blockIdx.x] = ws[0] + ws[1] + ws[2] + ws[3];
}

// phase B: exclusive scan of NB block sums (single small block)
__global__ __launch_bounds__(512) void scanB_k(const int* __restrict__ bsum, int* __restrict__ bpre,
                                               int* __restrict__ offsets) {
    __shared__ int sh[512];
    int t = threadIdx.x;
    sh[t] = (t < NB) ? bsum[t] : 0;
    __syncthreads();
    for (int off = 1; off < 512; off <<= 1) {
        int v = (t >= off) ? sh[t - off] : 0;
        __syncthreads();
        sh[t] += v;
        __syncthreads();
    }
    if (t < NB) bpre[t] = (t == 0) ? 0 : sh[t - 1];
    if (t == 0) offsets[NN] = EE;
}

// phase C: in-block exclusive scan + add block prefix
__global__ __launch_bounds__(256) void scanC_k(const int* __restrict__ cnt, const int* __restrict__ bpre,
                                               int* __restrict__ offsets, int* __restrict__ cursor) {
    int t = threadIdx.x;
    int i = blockIdx.x * 256 + t;
    int lane = t & 63, wave = t >> 6;
    int c = (i < NN) ? cnt[i] : 0;
    int x = c;
#pragma unroll
    for (int off = 1; off < 64; off <<= 1) {
        int v = __shfl_up(x, off);
        if (lane >= off) x += v;
    }
    __shared__ int wsum[4];
    if (lane == 63) wsum[wave] = x;
    __syncthreads();
    __shared__ int wpre[4];
    if (t == 0) {
        wpre[0] = 0;
        wpre[1] = wsum[0];
        wpre[2] = wsum[0] + wsum[1];
        wpre[3] = wsum[0] + wsum[1] + wsum[2];
    }
    __syncthreads();
    if (i < NN) {
        int off = bpre[blockIdx.x] + wpre[wave] + (x - c);  // exclusive
        offsets[i] = off;
        cursor[i] = off;
    }
}

__global__ __launch_bounds__(256) void scatter_k(const int* __restrict__ src,
                                                 const int* __restrict__ dst,
                                                 int* __restrict__ cursor,
                                                 int* __restrict__ ssrc) {
    int e = blockIdx.x * 256 + threadIdx.x;
    int d = dst[e];
    int p = atomicAdd(&cursor[d], 1);
    ssrc[p] = src[e];
}

// ---------------- GEMM: Y = X @ W (+bias+leaky | +alpha dots) ----------------
// 128x128 tile per 256-thread block; KC=32 chunked staging; 32 KB LDS.
// Thread (tm = t>>4, tn = t&15) computes rows {tm*4+i, 64+tm*4+i} x cols {tn*4+j, 64+tn*4+j}.
// +-64 split keeps LDS reads at <=2-way bank aliasing (free).
template <int MODE>
__global__ __launch_bounds__(256, 3) void gemm_k(const float* __restrict__ X,
                                                 const float* __restrict__ W,
                                                 const float* __restrict__ bias,
                                                 const float* __restrict__ av_src,
                                                 const float* __restrict__ av_dst,
                                                 float* __restrict__ Y,
                                                 float* __restrict__ alpha_src,
                                                 float* __restrict__ alpha_dst) {
    __shared__ float sX[32 * 128];  // [k][m] transposed, 16 KB
    __shared__ float sW[32 * 128];  // [k][n], 16 KB
    int t = threadIdx.x;
    int row0 = blockIdx.x * 128;
    int tm = t >> 4, tn = t & 15;

    float acc[2][2][4][4] = {};  // [row half][col half][i][j]

    const float4* W4 = (const float4*)W;
    float4* sW4 = (float4*)sW;
    float4* sX4 = (float4*)sX;

    int xm = t >> 1;                 // tile row this thread stages
    int xrow = row0 + xm;
    bool xvalid = xrow < NN;
    const float4* Xrow4 = (const float4*)(X + (size_t)xrow * DD);
    int xko = (t & 1) * 16;

    for (int kc = 0; kc < DD; kc += 32) {
        __syncthreads();
        // stage X transposed: sX[k][m] = X[row0+m][kc+k]  (2-way write aliasing = free)
#pragma unroll
        for (int q = 0; q < 4; q++) {
            int ko = xko + q * 4;
            float4 xv = xvalid ? Xrow4[(kc + ko) >> 2] : make_float4(0.f, 0.f, 0.f, 0.f);
            sX[(ko + 0) * 128 + xm] = xv.x;
            sX[(ko + 1) * 128 + xm] = xv.y;
            sX[(ko + 2) * 128 + xm] = xv.z;
            sX[(ko + 3) * 128 + xm] = xv.w;
        }
        // stage W: straight copy, coalesced float4
#pragma unroll
        for (int q = 0; q < 4; q++) {
            int idx = q * 256 + t;           // float4 index in [0,1024)
            sW4[idx] = W4[kc * 32 + idx];
        }
        __syncthreads();
#pragma unroll 8
        for (int k = 0; k < 32; k++) {
            float4 x0 = sX4[k * 32 + tm];
            float4 x1 = sX4[k * 32 + 16 + tm];
            float4 w0 = sW4[k * 32 + tn];
            float4 w1 = sW4[k * 32 + 16 + tn];
            float xa[2][4] = {{x0.x, x0.y, x0.z, x0.w}, {x1.x, x1.y, x1.z, x1.w}};
            float wb[2][4] = {{w0.x, w0.y, w0.z, w0.w}, {w1.x, w1.y, w1.z, w1.w}};
#pragma unroll
            for (int a = 0; a < 2; a++)
#pragma unroll
                for (int b = 0; b < 2; b++)
#pragma unroll
                    for (int i = 0; i < 4; i++)
#pragma unroll
                        for (int j = 0; j < 4; j++)
                            acc[a][b][i][j] += xa[a][i] * wb[b][j];
        }
    }

    if (MODE == 0) {
        float4 ba = *(const float4*)(bias + tn * 4);
        float4 bb = *(const float4*)(bias + 64 + tn * 4);
#pragma unroll
        for (int a = 0; a < 2; a++) {
#pragma unroll
            for (int i = 0; i < 4; i++) {
                int row = row0 + a * 64 + tm * 4 + i;
                if (row < NN) {
                    float o0[4] = {acc[a][0][i][0] + ba.x, acc[a][0][i][1] + ba.y,
                                   acc[a][0][i][2] + ba.z, acc[a][0][i][3] + ba.w};
                    float o1[4] = {acc[a][1][i][0] + bb.x, acc[a][1][i][1] + bb.y,
                                   acc[a][1][i][2] + bb.z, acc[a][1][i][3] + bb.w};
#pragma unroll
                    for (int j = 0; j < 4; j++) {
                        o0[j] = o0[j] > 0.f ? o0[j] : 0.01f * o0[j];
                        o1[j] = o1[j] > 0.f ? o1[j] : 0.01f * o1[j];
                    }
                    *(float4*)&Y[(size_t)row * DD + tn * 4] = make_float4(o0[0], o0[1], o0[2], o0[3]);
                    *(float4*)&Y[(size_t)row * DD + 64 + tn * 4] = make_float4(o1[0], o1[1], o1[2], o1[3]);
                }
            }
        }
    } else {
        float4 asa = *(const float4*)(av_src + tn * 4);
        float4 asb = *(const float4*)(av_src + 64 + tn * 4);
        float4 ada = *(const float4*)(av_dst + tn * 4);
        float4 adb = *(const float4*)(av_dst + 64 + tn * 4);
#pragma unroll
        for (int a = 0; a < 2; a++) {
#pragma unroll
            for (int i = 0; i < 4; i++) {
                int row = row0 + a * 64 + tm * 4 + i;
                float4 o0 = make_float4(acc[a][0][i][0], acc[a][0][i][1], acc[a][0][i][2], acc[a][0][i][3]);
                float4 o1 = make_float4(acc[a][1][i][0], acc[a][1][i][1], acc[a][1][i][2], acc[a][1][i][3]);
                if (row < NN) {
                    *(float4*)&Y[(size_t)row * DD + tn * 4] = o0;
                    *(float4*)&Y[(size_t)row * DD + 64 + tn * 4] = o1;
                }
                float pa = o0.x * asa.x + o0.y * asa.y + o0.z * asa.z + o0.w * asa.w
                         + o1.x * asb.x + o1.y * asb.y + o1.z * asb.z + o1.w * asb.w;
                float pb = o0.x * ada.x + o0.y * ada.y + o0.z * ada.z + o0.w * ada.w
                         + o1.x * adb.x + o1.y * adb.y + o1.z * adb.z + o1.w * adb.w;
#pragma unroll
                for (int off = 8; off >= 1; off >>= 1) {
                    pa += __shfl_xor(pa, off);
                    pb += __shfl_xor(pb, off);
                }
                if (tn == 0 && row < NN) {
                    alpha_src[row] = pa;
                    alpha_dst[row] = pb;
                }
            }
        }
    }
}

// ---------------- Per-dst aggregation + softmax + bias + LN + leaky ----------------
// one wave per dst node; lane c owns channels 2c, 2c+1
__global__ __launch_bounds__(256) void agg_k(const float* __restrict__ tmp,
                                             const int* __restrict__ ssrc,
                                             const int* __restrict__ offsets,
                                             const float* __restrict__ alpha_src,
                                             const float* __restrict__ alpha_dst,
                                             const float* __restrict__ bias,
                                             const float* __restrict__ gamma,
                                             const float* __restrict__ beta,
                                             float* __restrict__ out) {
    int wid = (blockIdx.x * 256 + threadIdx.x) >> 6;
    int lane = threadIdx.x & 63;
    int beg = offsets[wid], end = offsets[wid + 1];
    float adst = alpha_dst[wid];

    // pass 1: segment max
    float m = -INFINITY;
    for (int j = beg + lane; j < end; j += 64) {
        int s = ssrc[j];
        float e = alpha_src[s] + adst;
        e = e > 0.f ? e : 0.2f * e;
        m = fmaxf(m, e);
    }
#pragma unroll
    for (int off = 32; off >= 1; off >>= 1) m = fmaxf(m, __shfl_xor(m, off));

    // pass 2: exp weights + accumulate (unnormalized), track denom
    float2 accA = make_float2(0.f, 0.f);
    float2 accB = make_float2(0.f, 0.f);
    float dsum = 0.f;
    const float2* tmp2 = (const float2*)tmp;
    for (int base = beg; base < end; base += 64) {
        int j = base + lane;
        float ex = 0.f; int s = 0;
        if (j < end) {
            s = ssrc[j];
            float e = alpha_src[s] + adst;
            e = e > 0.f ? e : 0.2f * e;
            ex = __expf(e - m);
        }
        dsum += ex;
        int cntr = end - base; if (cntr > 64) cntr = 64;
        int jj = 0;
        for (; jj + 3 < cntr; jj += 4) {
            float w0 = __shfl(ex, jj),     w1 = __shfl(ex, jj + 1);
            float w2 = __shfl(ex, jj + 2), w3 = __shfl(ex, jj + 3);
            int   s0 = __shfl(s, jj),      s1 = __shfl(s, jj + 1);
            int   s2 = __shfl(s, jj + 2),  s3 = __shfl(s, jj + 3);
            float2 h0 = tmp2[(size_t)s0 * 64 + lane];
            float2 h1 = tmp2[(size_t)s1 * 64 + lane];
            float2 h2 = tmp2[(size_t)s2 * 64 + lane];
            float2 h3 = tmp2[(size_t)s3 * 64 + lane];
            accA.x += w0 * h0.x; accA.y += w0 * h0.y;
            accB.x += w1 * h1.x; accB.y += w1 * h1.y;
            accA.x += w2 * h2.x; accA.y += w2 * h2.y;
            accB.x += w3 * h3.x; accB.y += w3 * h3.y;
        }
        for (; jj < cntr; jj++) {
            float w = __shfl(ex, jj);
            int ss = __shfl(s, jj);
            float2 hv = tmp2[(size_t)ss * 64 + lane];
            accA.x += w * hv.x;
            accA.y += w * hv.y;
        }
    }
#pragma unroll
    for (int off = 32; off >= 1; off >>= 1) dsum += __shfl_xor(dsum, off);
    float inv = 1.0f / (dsum + 1e-16f);

    float ax = (accA.x + accB.x) * inv + bias[2 * lane];
    float ay = (accA.y + accB.y) * inv + bias[2 * lane + 1];

    // layernorm over 128 channels (2 per lane)
    float s1 = ax + ay;
#pragma unroll
    for (int off = 32; off >= 1; off >>= 1) s1 += __shfl_xor(s1, off);
    float mu = s1 * (1.0f / 128.0f);
    float dx = ax - mu, dy = ay - mu;
    float s2 = dx * dx + dy * dy;
#pragma unroll
    for (int off = 32; off >= 1; off >>= 1) s2 += __shfl_xor(s2, off);
    float rstd = rsqrtf(s2 * (1.0f / 128.0f) + 1e-5f);

    float yx = dx * rstd * gamma[2 * lane] + beta[2 * lane];
    float yy = dy * rstd * gamma[2 * lane + 1] + beta[2 * lane + 1];
    yx = yx > 0.f ? yx : 0.01f * yx;
    yy = yy > 0.f ? yy : 0.01f * yy;
    ((float2*)out)[(size_t)wid * 64 + lane] = make_float2(yx, yy);
}

extern "C" void kernel_launch(void* const* d_in, const int* in_sizes, int n_in,
                              void* d_out, int out_size, void* d_ws, size_t ws_size,
                              hipStream_t stream) {
    const float* x       = (const float*)d_in[0];
    const int*   ei      = (const int*)d_in[1];
    const float* W_in    = (const float*)d_in[2];
    const float* b_in    = (const float*)d_in[3];
    const float* Wl      = (const float*)d_in[4];
    const float* att_src = (const float*)d_in[5];
    const float* att_dst = (const float*)d_in[6];
    const float* bias_l  = (const float*)d_in[7];
    const float* gamma   = (const float*)d_in[8];
    const float* beta    = (const float*)d_in[9];
    float* out = (float*)d_out;

    char* ws = (char*)d_ws;
    float* tmp       = (float*)ws; ws += (size_t)NN * DD * 4;   // 51.2 MB
    float* alpha_src = (float*)ws; ws += (size_t)NN * 4;
    float* alpha_dst = (float*)ws; ws += (size_t)NN * 4;
    int*   cnt       = (int*)ws;   ws += (size_t)NN * 4;
    int*   offsets   = (int*)ws;   ws += (size_t)(NN + 4) * 4;
    int*   cursor    = (int*)ws;   ws += (size_t)NN * 4;
    int*   ssrc      = (int*)ws;   ws += (size_t)EE * 4;
    int*   bsum      = (int*)ws;   ws += (size_t)(NB + 8) * 4;
    int*   bpre      = (int*)ws;   ws += (size_t)(NB + 8) * 4;

    const int* esrc = ei;
    const int* edst = ei + EE;

    // CSR by dst (edges constant within a launch)
    hipMemsetAsync(cnt, 0, (size_t)NN * 4, stream);
    hist_k<<<EE / 256, 256, 0, stream>>>(edst, cnt);
    scanA_k<<<NB, 256, 0, stream>>>(cnt, bsum);
    scanB_k<<<1, 512, 0, stream>>>(bsum, bpre, offsets);
    scanC_k<<<NB, 256, 0, stream>>>(cnt, bpre, offsets, cursor);
    scatter_k<<<EE / 256, 256, 0, stream>>>(esrc, edst, cursor, ssrc);

    const int gemm_grid = (NN + 127) / 128;  // 782

    // input projection: h0 = leaky(x @ W_in + b_in)
    gemm_k<0><<<gemm_grid, 256, 0, stream>>>(x, W_in, b_in, nullptr, nullptr, out, nullptr, nullptr);

    for (int i = 0; i < 4; i++) {
        gemm_k<1><<<gemm_grid, 256, 0, stream>>>(out, Wl + (size_t)i * DD * DD, nullptr,
                                                 att_src + (size_t)i * DD, att_dst + (size_t)i * DD,
                                                 tmp, alpha_src, alpha_dst);
        agg_k<<<NN / 4, 256, 0, stream>>>(tmp, ssrc, offsets, alpha_src, alpha_dst,
                                          bias_l + (size_t)i * DD, gamma + (size_t)i * DD,
                                          beta + (size_t)i * DD, out);
    }
}

// Round 4
// 876.971 us; speedup vs baseline: 1.8403x; 1.1820x over previous
//
#include <hip/hip_runtime.h>
#include <hip/hip_fp16.h>
#include <math.h>

#define NN 100000
#define EE 1600000
#define DD 128
#define NB ((NN + 255) / 256)   // 391 scan blocks

// ---------------- CSR build ----------------
__global__ __launch_bounds__(256) void hist_k(const int* __restrict__ dst, int* __restrict__ cnt) {
    int e = blockIdx.x * 256 + threadIdx.x;
    atomicAdd(&cnt[dst[e]], 1);
}

// phase A: per-block partial sums of cnt
__global__ __launch_bounds__(256) void scanA_k(const int* __restrict__ cnt, int* __restrict__ bsum) {
    int i = blockIdx.x * 256 + threadIdx.x;
    int c = (i < NN) ? cnt[i] : 0;
#pragma unroll
    for (int off = 32; off >= 1; off >>= 1) c += __shfl_xor(c, off);
    __shared__ int ws[4];
    if ((threadIdx.x & 63) == 0) ws[threadIdx.x >> 6] = c;
    __syncthreads();
    if (threadIdx.x == 0) bsum[blockIdx.x] = ws[0] + ws[1] + ws[2] + ws[3];
}

// phase B: exclusive scan of NB block sums (single small block)
__global__ __launch_bounds__(512) void scanB_k(const int* __restrict__ bsum, int* __restrict__ bpre,
                                               int* __restrict__ offsets) {
    __shared__ int sh[512];
    int t = threadIdx.x;
    sh[t] = (t < NB) ? bsum[t] : 0;
    __syncthreads();
    for (int off = 1; off < 512; off <<= 1) {
        int v = (t >= off) ? sh[t - off] : 0;
        __syncthreads();
        sh[t] += v;
        __syncthreads();
    }
    if (t < NB) bpre[t] = (t == 0) ? 0 : sh[t - 1];
    if (t == 0) offsets[NN] = EE;
}

// phase C: in-block exclusive scan + add block prefix
__global__ __launch_bounds__(256) void scanC_k(const int* __restrict__ cnt, const int* __restrict__ bpre,
                                               int* __restrict__ offsets, int* __restrict__ cursor) {
    int t = threadIdx.x;
    int i = blockIdx.x * 256 + t;
    int lane = t & 63, wave = t >> 6;
    int c = (i < NN) ? cnt[i] : 0;
    int x = c;
#pragma unroll
    for (int off = 1; off < 64; off <<= 1) {
        int v = __shfl_up(x, off);
        if (lane >= off) x += v;
    }
    __shared__ int wsum[4];
    if (lane == 63) wsum[wave] = x;
    __syncthreads();
    __shared__ int wpre[4];
    if (t == 0) {
        wpre[0] = 0;
        wpre[1] = wsum[0];
        wpre[2] = wsum[0] + wsum[1];
        wpre[3] = wsum[0] + wsum[1] + wsum[2];
    }
    __syncthreads();
    if (i < NN) {
        int off = bpre[blockIdx.x] + wpre[wave] + (x - c);  // exclusive
        offsets[i] = off;
        cursor[i] = off;
    }
}

__global__ __launch_bounds__(256) void scatter_k(const int* __restrict__ src,
                                                 const int* __restrict__ dst,
                                                 int* __restrict__ cursor,
                                                 int* __restrict__ ssrc) {
    int e = blockIdx.x * 256 + threadIdx.x;
    int d = dst[e];
    int p = atomicAdd(&cursor[d], 1);
    ssrc[p] = src[e];
}

// ---------------- GEMM: Y = X @ W (+bias+leaky | +alpha dots) ----------------
// 128x128 tile per 256-thread block; KC=32 chunked staging; 32 KB LDS.
// MODE 0: Yf = leaky(X@W + bias, 0.01)  (fp32 out)
// MODE 1: Yh = fp16(X@W); alpha_src/dst from fp32 accumulators
template <int MODE>
__global__ __launch_bounds__(256, 3) void gemm_k(const float* __restrict__ X,
                                                 const float* __restrict__ W,
                                                 const float* __restrict__ bias,
                                                 const float* __restrict__ av_src,
                                                 const float* __restrict__ av_dst,
                                                 float* __restrict__ Yf,
                                                 __half* __restrict__ Yh,
                                                 float* __restrict__ alpha_src,
                                                 float* __restrict__ alpha_dst) {
    __shared__ float sX[32 * 128];  // [k][m] transposed, 16 KB
    __shared__ float sW[32 * 128];  // [k][n], 16 KB
    int t = threadIdx.x;
    int row0 = blockIdx.x * 128;
    int tm = t >> 4, tn = t & 15;

    float acc[2][2][4][4] = {};  // [row half][col half][i][j]

    const float4* W4 = (const float4*)W;
    float4* sW4 = (float4*)sW;
    float4* sX4 = (float4*)sX;

    int xm = t >> 1;
    int xrow = row0 + xm;
    bool xvalid = xrow < NN;
    const float4* Xrow4 = (const float4*)(X + (size_t)xrow * DD);
    int xko = (t & 1) * 16;

    for (int kc = 0; kc < DD; kc += 32) {
        __syncthreads();
#pragma unroll
        for (int q = 0; q < 4; q++) {
            int ko = xko + q * 4;
            float4 xv = xvalid ? Xrow4[(kc + ko) >> 2] : make_float4(0.f, 0.f, 0.f, 0.f);
            sX[(ko + 0) * 128 + xm] = xv.x;
            sX[(ko + 1) * 128 + xm] = xv.y;
            sX[(ko + 2) * 128 + xm] = xv.z;
            sX[(ko + 3) * 128 + xm] = xv.w;
        }
#pragma unroll
        for (int q = 0; q < 4; q++) {
            int idx = q * 256 + t;
            sW4[idx] = W4[kc * 32 + idx];
        }
        __syncthreads();
#pragma unroll 8
        for (int k = 0; k < 32; k++) {
            float4 x0 = sX4[k * 32 + tm];
            float4 x1 = sX4[k * 32 + 16 + tm];
            float4 w0 = sW4[k * 32 + tn];
            float4 w1 = sW4[k * 32 + 16 + tn];
            float xa[2][4] = {{x0.x, x0.y, x0.z, x0.w}, {x1.x, x1.y, x1.z, x1.w}};
            float wb[2][4] = {{w0.x, w0.y, w0.z, w0.w}, {w1.x, w1.y, w1.z, w1.w}};
#pragma unroll
            for (int a = 0; a < 2; a++)
#pragma unroll
                for (int b = 0; b < 2; b++)
#pragma unroll
                    for (int i = 0; i < 4; i++)
#pragma unroll
                        for (int j = 0; j < 4; j++)
                            acc[a][b][i][j] += xa[a][i] * wb[b][j];
        }
    }

    if (MODE == 0) {
        float4 ba = *(const float4*)(bias + tn * 4);
        float4 bb = *(const float4*)(bias + 64 + tn * 4);
#pragma unroll
        for (int a = 0; a < 2; a++) {
#pragma unroll
            for (int i = 0; i < 4; i++) {
                int row = row0 + a * 64 + tm * 4 + i;
                if (row < NN) {
                    float o0[4] = {acc[a][0][i][0] + ba.x, acc[a][0][i][1] + ba.y,
                                   acc[a][0][i][2] + ba.z, acc[a][0][i][3] + ba.w};
                    float o1[4] = {acc[a][1][i][0] + bb.x, acc[a][1][i][1] + bb.y,
                                   acc[a][1][i][2] + bb.z, acc[a][1][i][3] + bb.w};
#pragma unroll
                    for (int j = 0; j < 4; j++) {
                        o0[j] = o0[j] > 0.f ? o0[j] : 0.01f * o0[j];
                        o1[j] = o1[j] > 0.f ? o1[j] : 0.01f * o1[j];
                    }
                    *(float4*)&Yf[(size_t)row * DD + tn * 4] = make_float4(o0[0], o0[1], o0[2], o0[3]);
                    *(float4*)&Yf[(size_t)row * DD + 64 + tn * 4] = make_float4(o1[0], o1[1], o1[2], o1[3]);
                }
            }
        }
    } else {
        float4 asa = *(const float4*)(av_src + tn * 4);
        float4 asb = *(const float4*)(av_src + 64 + tn * 4);
        float4 ada = *(const float4*)(av_dst + tn * 4);
        float4 adb = *(const float4*)(av_dst + 64 + tn * 4);
#pragma unroll
        for (int a = 0; a < 2; a++) {
#pragma unroll
            for (int i = 0; i < 4; i++) {
                int row = row0 + a * 64 + tm * 4 + i;
                float4 o0 = make_float4(acc[a][0][i][0], acc[a][0][i][1], acc[a][0][i][2], acc[a][0][i][3]);
                float4 o1 = make_float4(acc[a][1][i][0], acc[a][1][i][1], acc[a][1][i][2], acc[a][1][i][3]);
                if (row < NN) {
                    // pack 4 ch -> 4 halves (8 B), two stores per row half
                    union { __half2 h2[2]; uint2 u; } p0, p1;
                    p0.h2[0] = __floats2half2_rn(o0.x, o0.y);
                    p0.h2[1] = __floats2half2_rn(o0.z, o0.w);
                    p1.h2[0] = __floats2half2_rn(o1.x, o1.y);
                    p1.h2[1] = __floats2half2_rn(o1.z, o1.w);
                    *(uint2*)&Yh[(size_t)row * DD + tn * 4] = p0.u;
                    *(uint2*)&Yh[(size_t)row * DD + 64 + tn * 4] = p1.u;
                }
                float pa = o0.x * asa.x + o0.y * asa.y + o0.z * asa.z + o0.w * asa.w
                         + o1.x * asb.x + o1.y * asb.y + o1.z * asb.z + o1.w * asb.w;
                float pb = o0.x * ada.x + o0.y * ada.y + o0.z * ada.z + o0.w * ada.w
                         + o1.x * adb.x + o1.y * adb.y + o1.z * adb.z + o1.w * adb.w;
#pragma unroll
                for (int off = 8; off >= 1; off >>= 1) {
                    pa += __shfl_xor(pa, off);
                    pb += __shfl_xor(pb, off);
                }
                if (tn == 0 && row < NN) {
                    alpha_src[row] = pa;
                    alpha_dst[row] = pb;
                }
            }
        }
    }
}

// ---------------- Per-dst aggregation + softmax + bias + LN + leaky ----------------
// one wave per dst node; lane c owns channels 2c, 2c+1 (one __half2 / 4 B per lane per edge)
__global__ __launch_bounds__(256) void agg_k(const __half* __restrict__ tmp,
                                             const int* __restrict__ ssrc,
                                             const int* __restrict__ offsets,
                                             const float* __restrict__ alpha_src,
                                             const float* __restrict__ alpha_dst,
                                             const float* __restrict__ bias,
                                             const float* __restrict__ gamma,
                                             const float* __restrict__ beta,
                                             float* __restrict__ out) {
    int wid = (blockIdx.x * 256 + threadIdx.x) >> 6;
    int lane = threadIdx.x & 63;
    int beg = offsets[wid], end = offsets[wid + 1];
    float adst = alpha_dst[wid];

    // pass 1: segment max
    float m = -INFINITY;
    for (int j = beg + lane; j < end; j += 64) {
        int s = ssrc[j];
        float e = alpha_src[s] + adst;
        e = e > 0.f ? e : 0.2f * e;
        m = fmaxf(m, e);
    }
#pragma unroll
    for (int off = 32; off >= 1; off >>= 1) m = fmaxf(m, __shfl_xor(m, off));

    // pass 2: exp weights + accumulate (unnormalized), track denom
    float2 accA = make_float2(0.f, 0.f);
    float2 accB = make_float2(0.f, 0.f);
    float dsum = 0.f;
    const __half2* tmp2 = (const __half2*)tmp;
    for (int base = beg; base < end; base += 64) {
        int j = base + lane;
        float ex = 0.f; int s = 0;
        if (j < end) {
            s = ssrc[j];
            float e = alpha_src[s] + adst;
            e = e > 0.f ? e : 0.2f * e;
            ex = __expf(e - m);
        }
        dsum += ex;
        int cntr = end - base; if (cntr > 64) cntr = 64;
        int jj = 0;
        for (; jj + 3 < cntr; jj += 4) {
            float w0 = __shfl(ex, jj),     w1 = __shfl(ex, jj + 1);
            float w2 = __shfl(ex, jj + 2), w3 = __shfl(ex, jj + 3);
            int   s0 = __shfl(s, jj),      s1 = __shfl(s, jj + 1);
            int   s2 = __shfl(s, jj + 2),  s3 = __shfl(s, jj + 3);
            float2 h0 = __half22float2(tmp2[(size_t)s0 * 64 + lane]);
            float2 h1 = __half22float2(tmp2[(size_t)s1 * 64 + lane]);
            float2 h2 = __half22float2(tmp2[(size_t)s2 * 64 + lane]);
            float2 h3 = __half22float2(tmp2[(size_t)s3 * 64 + lane]);
            accA.x += w0 * h0.x; accA.y += w0 * h0.y;
            accB.x += w1 * h1.x; accB.y += w1 * h1.y;
            accA.x += w2 * h2.x; accA.y += w2 * h2.y;
            accB.x += w3 * h3.x; accB.y += w3 * h3.y;
        }
        for (; jj < cntr; jj++) {
            float w = __shfl(ex, jj);
            int ss = __shfl(s, jj);
            float2 hv = __half22float2(tmp2[(size_t)ss * 64 + lane]);
            accA.x += w * hv.x;
            accA.y += w * hv.y;
        }
    }
#pragma unroll
    for (int off = 32; off >= 1; off >>= 1) dsum += __shfl_xor(dsum, off);
    float inv = 1.0f / (dsum + 1e-16f);

    float ax = (accA.x + accB.x) * inv + bias[2 * lane];
    float ay = (accA.y + accB.y) * inv + bias[2 * lane + 1];

    // layernorm over 128 channels (2 per lane)
    float s1 = ax + ay;
#pragma unroll
    for (int off = 32; off >= 1; off >>= 1) s1 += __shfl_xor(s1, off);
    float mu = s1 * (1.0f / 128.0f);
    float dx = ax - mu, dy = ay - mu;
    float s2 = dx * dx + dy * dy;
#pragma unroll
    for (int off = 32; off >= 1; off >>= 1) s2 += __shfl_xor(s2, off);
    float rstd = rsqrtf(s2 * (1.0f / 128.0f) + 1e-5f);

    float yx = dx * rstd * gamma[2 * lane] + beta[2 * lane];
    float yy = dy * rstd * gamma[2 * lane + 1] + beta[2 * lane + 1];
    yx = yx > 0.f ? yx : 0.01f * yx;
    yy = yy > 0.f ? yy : 0.01f * yy;
    ((float2*)out)[(size_t)wid * 64 + lane] = make_float2(yx, yy);
}

extern "C" void kernel_launch(void* const* d_in, const int* in_sizes, int n_in,
                              void* d_out, int out_size, void* d_ws, size_t ws_size,
                              hipStream_t stream) {
    const float* x       = (const float*)d_in[0];
    const int*   ei      = (const int*)d_in[1];
    const float* W_in    = (const float*)d_in[2];
    const float* b_in    = (const float*)d_in[3];
    const float* Wl      = (const float*)d_in[4];
    const float* att_src = (const float*)d_in[5];
    const float* att_dst = (const float*)d_in[6];
    const float* bias_l  = (const float*)d_in[7];
    const float* gamma   = (const float*)d_in[8];
    const float* beta    = (const float*)d_in[9];
    float* out = (float*)d_out;

    char* ws = (char*)d_ws;
    __half* tmp      = (__half*)ws; ws += (size_t)NN * DD * 2;  // 25.6 MB
    float* alpha_src = (float*)ws; ws += (size_t)NN * 4;
    float* alpha_dst = (float*)ws; ws += (size_t)NN * 4;
    int*   cnt       = (int*)ws;   ws += (size_t)NN * 4;
    int*   offsets   = (int*)ws;   ws += (size_t)(NN + 4) * 4;
    int*   cursor    = (int*)ws;   ws += (size_t)NN * 4;
    int*   ssrc      = (int*)ws;   ws += (size_t)EE * 4;
    int*   bsum      = (int*)ws;   ws += (size_t)(NB + 8) * 4;
    int*   bpre      = (int*)ws;   ws += (size_t)(NB + 8) * 4;

    const int* esrc = ei;
    const int* edst = ei + EE;

    // CSR by dst (edges constant within a launch)
    hipMemsetAsync(cnt, 0, (size_t)NN * 4, stream);
    hist_k<<<EE / 256, 256, 0, stream>>>(edst, cnt);
    scanA_k<<<NB, 256, 0, stream>>>(cnt, bsum);
    scanB_k<<<1, 512, 0, stream>>>(bsum, bpre, offsets);
    scanC_k<<<NB, 256, 0, stream>>>(cnt, bpre, offsets, cursor);
    scatter_k<<<EE / 256, 256, 0, stream>>>(esrc, edst, cursor, ssrc);

    const int gemm_grid = (NN + 127) / 128;  // 782

    // input projection: h0 = leaky(x @ W_in + b_in)
    gemm_k<0><<<gemm_grid, 256, 0, stream>>>(x, W_in, b_in, nullptr, nullptr, out, nullptr, nullptr, nullptr);

    for (int i = 0; i < 4; i++) {
        gemm_k<1><<<gemm_grid, 256, 0, stream>>>(out, Wl + (size_t)i * DD * DD, nullptr,
                                                 att_src + (size_t)i * DD, att_dst + (size_t)i * DD,
                                                 nullptr, tmp, alpha_src, alpha_dst);
        agg_k<<<NN / 4, 256, 0, stream>>>(tmp, ssrc, offsets, alpha_src, alpha_dst,
                                          bias_l + (size_t)i * DD, gamma + (size_t)i * DD,
                                          beta + (size_t)i * DD, out);
    }
}

// Round 5
// 742.440 us; speedup vs baseline: 2.1738x; 1.1812x over previous
//
#include <hip/hip_runtime.h>
#include <hip/hip_fp16.h>
#include <math.h>

#define NN 100000
#define EE 1600000
#define DD 128
#define NBUCK 196          // ceil(NN / 512) buckets of 512 dst nodes
#define NBLKP 196          // partition blocks, 8192 edges each (196*8192 >= EE)
#define EPB 8192           // edges per partition block

// ---------- bucketed CSR build ----------
// 1) per-(bucket, partition-block) histogram
__global__ __launch_bounds__(256) void part_hist_k(const int* __restrict__ dst, int* __restrict__ bcnt) {
    __shared__ int lc[NBUCK];
    int t = threadIdx.x, blk = blockIdx.x;
    if (t < NBUCK) lc[t] = 0;
    __syncthreads();
    int e0 = blk * EPB;
    for (int i = t; i < EPB; i += 256) {
        int e = e0 + i;
        if (e < EE) atomicAdd(&lc[dst[e] >> 9], 1);
    }
    __syncthreads();
    if (t < NBUCK) bcnt[t * NBLKP + blk] = lc[t];
}

// 2) per-bucket exclusive scan over partition blocks
__global__ __launch_bounds__(256) void scanBB_k(const int* __restrict__ bcnt, int* __restrict__ ebase,
                                                int* __restrict__ btot) {
    __shared__ int sh[256];
    int t = threadIdx.x, b = blockIdx.x;
    int c = (t < NBLKP) ? bcnt[b * NBLKP + t] : 0;
    sh[t] = c;
    __syncthreads();
    for (int off = 1; off < 256; off <<= 1) {
        int v = (t >= off) ? sh[t - off] : 0;
        __syncthreads();
        sh[t] += v;
        __syncthreads();
    }
    if (t < NBLKP) ebase[b * NBLKP + t] = sh[t] - c;  // exclusive
    if (t == 255) btot[b] = sh[255];
}

// 3) exclusive scan of bucket totals
__global__ __launch_bounds__(256) void scanBT_k(const int* __restrict__ btot, int* __restrict__ bstart,
                                                int* __restrict__ offsets) {
    __shared__ int sh[256];
    int t = threadIdx.x;
    int c = (t < NBUCK) ? btot[t] : 0;
    sh[t] = c;
    __syncthreads();
    for (int off = 1; off < 256; off <<= 1) {
        int v = (t >= off) ? sh[t - off] : 0;
        __syncthreads();
        sh[t] += v;
        __syncthreads();
    }
    if (t < NBUCK) bstart[t] = sh[t] - c;
    if (t == 0) { bstart[NBUCK] = EE; offsets[NN] = EE; }
}

// 4) partition edges into bucket-grouped ebuf (src,dst) pairs
__global__ __launch_bounds__(256) void part_k(const int* __restrict__ src, const int* __restrict__ dst,
                                              const int* __restrict__ bstart, const int* __restrict__ ebase,
                                              int2* __restrict__ ebuf) {
    __shared__ int cur[NBUCK];
    int t = threadIdx.x, blk = blockIdx.x;
    if (t < NBUCK) cur[t] = bstart[t] + ebase[t * NBLKP + blk];
    __syncthreads();
    int e0 = blk * EPB;
    for (int i = t; i < EPB; i += 256) {
        int e = e0 + i;
        if (e < EE) {
            int s = src[e], d = dst[e];
            int p = atomicAdd(&cur[d >> 9], 1);
            ebuf[p] = make_int2(s, d);
        }
    }
}

// 5) per-bucket local counting sort: derive offsets[] and write ssrc grouped by dst
__global__ __launch_bounds__(512) void bucket_sort_k(const int2* __restrict__ ebuf,
                                                     const int* __restrict__ bstart,
                                                     int* __restrict__ offsets,
                                                     int* __restrict__ ssrc) {
    __shared__ int sh[512];
    __shared__ int cur[512];
    int t = threadIdx.x, b = blockIdx.x;
    int d0 = b << 9;
    int beg = bstart[b], end = bstart[b + 1];

    cur[t] = 0;
    __syncthreads();
    for (int e = beg + t; e < end; e += 512) atomicAdd(&cur[ebuf[e].y - d0], 1);
    __syncthreads();
    int c = cur[t];
    sh[t] = c;
    __syncthreads();
    for (int off = 1; off < 512; off <<= 1) {
        int v = (t >= off) ? sh[t - off] : 0;
        __syncthreads();
        sh[t] += v;
        __syncthreads();
    }
    int excl = sh[t] - c;
    if (d0 + t < NN) offsets[d0 + t] = beg + excl;
    cur[t] = beg + excl;
    __syncthreads();
    for (int e = beg + t; e < end; e += 512) {
        int2 ed = ebuf[e];
        int p = atomicAdd(&cur[ed.y - d0], 1);
        ssrc[p] = ed.x;
    }
}

// ---------------- GEMM: Y = X @ W (+bias+leaky | +alpha dots) ----------------
// 128x128 tile per 256-thread block; KC=32 chunked staging; 32 KB LDS.
// MODE 0: Yf = leaky(X@W + bias, 0.01)  (fp32 out)
// MODE 1: Yh = fp16(X@W); alpha_src/dst from fp32 accumulators
template <int MODE>
__global__ __launch_bounds__(256, 3) void gemm_k(const float* __restrict__ X,
                                                 const float* __restrict__ W,
                                                 const float* __restrict__ bias,
                                                 const float* __restrict__ av_src,
                                                 const float* __restrict__ av_dst,
                                                 float* __restrict__ Yf,
                                                 __half* __restrict__ Yh,
                                                 float* __restrict__ alpha_src,
                                                 float* __restrict__ alpha_dst) {
    __shared__ float sX[32 * 128];  // [k][m] transposed, 16 KB
    __shared__ float sW[32 * 128];  // [k][n], 16 KB
    int t = threadIdx.x;
    int row0 = blockIdx.x * 128;
    int tm = t >> 4, tn = t & 15;

    float acc[2][2][4][4] = {};

    const float4* W4 = (const float4*)W;
    float4* sW4 = (float4*)sW;
    float4* sX4 = (float4*)sX;

    int xm = t >> 1;
    int xrow = row0 + xm;
    bool xvalid = xrow < NN;
    const float4* Xrow4 = (const float4*)(X + (size_t)xrow * DD);
    int xko = (t & 1) * 16;

    for (int kc = 0; kc < DD; kc += 32) {
        __syncthreads();
#pragma unroll
        for (int q = 0; q < 4; q++) {
            int ko = xko + q * 4;
            float4 xv = xvalid ? Xrow4[(kc + ko) >> 2] : make_float4(0.f, 0.f, 0.f, 0.f);
            sX[(ko + 0) * 128 + xm] = xv.x;
            sX[(ko + 1) * 128 + xm] = xv.y;
            sX[(ko + 2) * 128 + xm] = xv.z;
            sX[(ko + 3) * 128 + xm] = xv.w;
        }
#pragma unroll
        for (int q = 0; q < 4; q++) {
            int idx = q * 256 + t;
            sW4[idx] = W4[kc * 32 + idx];
        }
        __syncthreads();
#pragma unroll 8
        for (int k = 0; k < 32; k++) {
            float4 x0 = sX4[k * 32 + tm];
            float4 x1 = sX4[k * 32 + 16 + tm];
            float4 w0 = sW4[k * 32 + tn];
            float4 w1 = sW4[k * 32 + 16 + tn];
            float xa[2][4] = {{x0.x, x0.y, x0.z, x0.w}, {x1.x, x1.y, x1.z, x1.w}};
            float wb[2][4] = {{w0.x, w0.y, w0.z, w0.w}, {w1.x, w1.y, w1.z, w1.w}};
#pragma unroll
            for (int a = 0; a < 2; a++)
#pragma unroll
                for (int b = 0; b < 2; b++)
#pragma unroll
                    for (int i = 0; i < 4; i++)
#pragma unroll
                        for (int j = 0; j < 4; j++)
                            acc[a][b][i][j] += xa[a][i] * wb[b][j];
        }
    }

    if (MODE == 0) {
        float4 ba = *(const float4*)(bias + tn * 4);
        float4 bb = *(const float4*)(bias + 64 + tn * 4);
#pragma unroll
        for (int a = 0; a < 2; a++) {
#pragma unroll
            for (int i = 0; i < 4; i++) {
                int row = row0 + a * 64 + tm * 4 + i;
                if (row < NN) {
                    float o0[4] = {acc[a][0][i][0] + ba.x, acc[a][0][i][1] + ba.y,
                                   acc[a][0][i][2] + ba.z, acc[a][0][i][3] + ba.w};
                    float o1[4] = {acc[a][1][i][0] + bb.x, acc[a][1][i][1] + bb.y,
                                   acc[a][1][i][2] + bb.z, acc[a][1][i][3] + bb.w};
#pragma unroll
                    for (int j = 0; j < 4; j++) {
                        o0[j] = o0[j] > 0.f ? o0[j] : 0.01f * o0[j];
                        o1[j] = o1[j] > 0.f ? o1[j] : 0.01f * o1[j];
                    }
                    *(float4*)&Yf[(size_t)row * DD + tn * 4] = make_float4(o0[0], o0[1], o0[2], o0[3]);
                    *(float4*)&Yf[(size_t)row * DD + 64 + tn * 4] = make_float4(o1[0], o1[1], o1[2], o1[3]);
                }
            }
        }
    } else {
        float4 asa = *(const float4*)(av_src + tn * 4);
        float4 asb = *(const float4*)(av_src + 64 + tn * 4);
        float4 ada = *(const float4*)(av_dst + tn * 4);
        float4 adb = *(const float4*)(av_dst + 64 + tn * 4);
#pragma unroll
        for (int a = 0; a < 2; a++) {
#pragma unroll
            for (int i = 0; i < 4; i++) {
                int row = row0 + a * 64 + tm * 4 + i;
                float4 o0 = make_float4(acc[a][0][i][0], acc[a][0][i][1], acc[a][0][i][2], acc[a][0][i][3]);
                float4 o1 = make_float4(acc[a][1][i][0], acc[a][1][i][1], acc[a][1][i][2], acc[a][1][i][3]);
                if (row < NN) {
                    union { __half2 h2[2]; uint2 u; } p0, p1;
                    p0.h2[0] = __floats2half2_rn(o0.x, o0.y);
                    p0.h2[1] = __floats2half2_rn(o0.z, o0.w);
                    p1.h2[0] = __floats2half2_rn(o1.x, o1.y);
                    p1.h2[1] = __floats2half2_rn(o1.z, o1.w);
                    *(uint2*)&Yh[(size_t)row * DD + tn * 4] = p0.u;
                    *(uint2*)&Yh[(size_t)row * DD + 64 + tn * 4] = p1.u;
                }
                float pa = o0.x * asa.x + o0.y * asa.y + o0.z * asa.z + o0.w * asa.w
                         + o1.x * asb.x + o1.y * asb.y + o1.z * asb.z + o1.w * asb.w;
                float pb = o0.x * ada.x + o0.y * ada.y + o0.z * ada.z + o0.w * ada.w
                         + o1.x * adb.x + o1.y * adb.y + o1.z * adb.z + o1.w * adb.w;
#pragma unroll
                for (int off = 8; off >= 1; off >>= 1) {
                    pa += __shfl_xor(pa, off);
                    pb += __shfl_xor(pb, off);
                }
                if (tn == 0 && row < NN) {
                    alpha_src[row] = pa;
                    alpha_dst[row] = pb;
                }
            }
        }
    }
}

// ---------------- Per-dst aggregation + softmax + bias + LN + leaky ----------------
// one wave per dst node; lane c owns channels 2c, 2c+1 (one __half2 / 4 B per lane per edge)
__global__ __launch_bounds__(256) void agg_k(const __half* __restrict__ tmp,
                                             const int* __restrict__ ssrc,
                                             const int* __restrict__ offsets,
                                             const float* __restrict__ alpha_src,
                                             const float* __restrict__ alpha_dst,
                                             const float* __restrict__ bias,
                                             const float* __restrict__ gamma,
                                             const float* __restrict__ beta,
                                             float* __restrict__ out) {
    int wid = (blockIdx.x * 256 + threadIdx.x) >> 6;
    int lane = threadIdx.x & 63;
    int beg = offsets[wid], end = offsets[wid + 1];
    float adst = alpha_dst[wid];

    float m = -INFINITY;
    for (int j = beg + lane; j < end; j += 64) {
        int s = ssrc[j];
        float e = alpha_src[s] + adst;
        e = e > 0.f ? e : 0.2f * e;
        m = fmaxf(m, e);
    }
#pragma unroll
    for (int off = 32; off >= 1; off >>= 1) m = fmaxf(m, __shfl_xor(m, off));

    float2 accA = make_float2(0.f, 0.f);
    float2 accB = make_float2(0.f, 0.f);
    float dsum = 0.f;
    const __half2* tmp2 = (const __half2*)tmp;
    for (int base = beg; base < end; base += 64) {
        int j = base + lane;
        float ex = 0.f; int s = 0;
        if (j < end) {
            s = ssrc[j];
            float e = alpha_src[s] + adst;
            e = e > 0.f ? e : 0.2f * e;
            ex = __expf(e - m);
        }
        dsum += ex;
        int cntr = end - base; if (cntr > 64) cntr = 64;
        int jj = 0;
        for (; jj + 3 < cntr; jj += 4) {
            float w0 = __shfl(ex, jj),     w1 = __shfl(ex, jj + 1);
            float w2 = __shfl(ex, jj + 2), w3 = __shfl(ex, jj + 3);
            int   s0 = __shfl(s, jj),      s1 = __shfl(s, jj + 1);
            int   s2 = __shfl(s, jj + 2),  s3 = __shfl(s, jj + 3);
            float2 h0 = __half22float2(tmp2[(size_t)s0 * 64 + lane]);
            float2 h1 = __half22float2(tmp2[(size_t)s1 * 64 + lane]);
            float2 h2 = __half22float2(tmp2[(size_t)s2 * 64 + lane]);
            float2 h3 = __half22float2(tmp2[(size_t)s3 * 64 + lane]);
            accA.x += w0 * h0.x; accA.y += w0 * h0.y;
            accB.x += w1 * h1.x; accB.y += w1 * h1.y;
            accA.x += w2 * h2.x; accA.y += w2 * h2.y;
            accB.x += w3 * h3.x; accB.y += w3 * h3.y;
        }
        for (; jj < cntr; jj++) {
            float w = __shfl(ex, jj);
            int ss = __shfl(s, jj);
            float2 hv = __half22float2(tmp2[(size_t)ss * 64 + lane]);
            accA.x += w * hv.x;
            accA.y += w * hv.y;
        }
    }
#pragma unroll
    for (int off = 32; off >= 1; off >>= 1) dsum += __shfl_xor(dsum, off);
    float inv = 1.0f / (dsum + 1e-16f);

    float ax = (accA.x + accB.x) * inv + bias[2 * lane];
    float ay = (accA.y + accB.y) * inv + bias[2 * lane + 1];

    float s1 = ax + ay;
#pragma unroll
    for (int off = 32; off >= 1; off >>= 1) s1 += __shfl_xor(s1, off);
    float mu = s1 * (1.0f / 128.0f);
    float dx = ax - mu, dy = ay - mu;
    float s2 = dx * dx + dy * dy;
#pragma unroll
    for (int off = 32; off >= 1; off >>= 1) s2 += __shfl_xor(s2, off);
    float rstd = rsqrtf(s2 * (1.0f / 128.0f) + 1e-5f);

    float yx = dx * rstd * gamma[2 * lane] + beta[2 * lane];
    float yy = dy * rstd * gamma[2 * lane + 1] + beta[2 * lane + 1];
    yx = yx > 0.f ? yx : 0.01f * yx;
    yy = yy > 0.f ? yy : 0.01f * yy;
    ((float2*)out)[(size_t)wid * 64 + lane] = make_float2(yx, yy);
}

extern "C" void kernel_launch(void* const* d_in, const int* in_sizes, int n_in,
                              void* d_out, int out_size, void* d_ws, size_t ws_size,
                              hipStream_t stream) {
    const float* x       = (const float*)d_in[0];
    const int*   ei      = (const int*)d_in[1];
    const float* W_in    = (const float*)d_in[2];
    const float* b_in    = (const float*)d_in[3];
    const float* Wl      = (const float*)d_in[4];
    const float* att_src = (const float*)d_in[5];
    const float* att_dst = (const float*)d_in[6];
    const float* bias_l  = (const float*)d_in[7];
    const float* gamma   = (const float*)d_in[8];
    const float* beta    = (const float*)d_in[9];
    float* out = (float*)d_out;

    char* ws = (char*)d_ws;
    __half* tmp      = (__half*)ws; ws += (size_t)NN * DD * 2;   // 25.6 MB
    float* alpha_src = (float*)ws;  ws += (size_t)NN * 4;
    float* alpha_dst = (float*)ws;  ws += (size_t)NN * 4;
    int*   offsets   = (int*)ws;    ws += (size_t)(NN + 4) * 4;
    int*   ssrc      = (int*)ws;    ws += (size_t)EE * 4;        // 6.4 MB
    int2*  ebuf      = (int2*)ws;   ws += (size_t)EE * 8;        // 12.8 MB
    int*   bcnt      = (int*)ws;    ws += (size_t)NBUCK * NBLKP * 4;
    int*   ebase     = (int*)ws;    ws += (size_t)NBUCK * NBLKP * 4;
    int*   btot      = (int*)ws;    ws += (size_t)(NBUCK + 4) * 4;
    int*   bstart    = (int*)ws;    ws += (size_t)(NBUCK + 4) * 4;

    const int* esrc = ei;
    const int* edst = ei + EE;

    // bucketed CSR build (edges constant within a launch)
    part_hist_k<<<NBLKP, 256, 0, stream>>>(edst, bcnt);
    scanBB_k<<<NBUCK, 256, 0, stream>>>(bcnt, ebase, btot);
    scanBT_k<<<1, 256, 0, stream>>>(btot, bstart, offsets);
    part_k<<<NBLKP, 256, 0, stream>>>(esrc, edst, bstart, ebase, ebuf);
    bucket_sort_k<<<NBUCK, 512, 0, stream>>>(ebuf, bstart, offsets, ssrc);

    const int gemm_grid = (NN + 127) / 128;  // 782

    // input projection: h0 = leaky(x @ W_in + b_in)
    gemm_k<0><<<gemm_grid, 256, 0, stream>>>(x, W_in, b_in, nullptr, nullptr, out, nullptr, nullptr, nullptr);

    for (int i = 0; i < 4; i++) {
        gemm_k<1><<<gemm_grid, 256, 0, stream>>>(out, Wl + (size_t)i * DD * DD, nullptr,
                                                 att_src + (size_t)i * DD, att_dst + (size_t)i * DD,
                                                 nullptr, tmp, alpha_src, alpha_dst);
        agg_k<<<NN / 4, 256, 0, stream>>>(tmp, ssrc, offsets, alpha_src, alpha_dst,
                                          bias_l + (size_t)i * DD, gamma + (size_t)i * DD,
                                          beta + (size_t)i * DD, out);
    }
}